// Round 1
// baseline (5901.757 us; speedup 1.0000x reference)
//
#include <hip/hip_runtime.h>

#define DIM 64
#define DEA 32

// ---------------------------------------------------------------------------
// Node linear: q = x@Wq+bq, k = x@Wk+bk, v = x@Wv+bv, agg = x@Ws+bs
// block=256 (4 waves), 16 nodes per block, weights staged in LDS.
// ---------------------------------------------------------------------------
__global__ __launch_bounds__(256) void node_lin_kernel(
    const float* __restrict__ x,
    const float* __restrict__ wq, const float* __restrict__ bq,
    const float* __restrict__ wk, const float* __restrict__ bk,
    const float* __restrict__ wv, const float* __restrict__ bv,
    const float* __restrict__ wsk, const float* __restrict__ bsk,
    float* __restrict__ q, float* __restrict__ k, float* __restrict__ v,
    float* __restrict__ agg, int n_nodes)
{
    __shared__ float lw[4][DIM * DIM];   // 64 KB
    __shared__ float lx[16][DIM];        // 4 KB
    const int tid = threadIdx.x;

    {
        const float* srcs[4] = {wq, wk, wv, wsk};
        #pragma unroll
        for (int m = 0; m < 4; ++m) {
            const float4* s4 = (const float4*)srcs[m];
            float4* d4 = (float4*)lw[m];
            #pragma unroll
            for (int i = 0; i < 4; ++i) d4[tid + i * 256] = s4[tid + i * 256];
        }
    }
    const int base = blockIdx.x * 16;
    {
        const int r = tid >> 4;
        const int c = (tid & 15) * 4;
        const int n = base + r;
        float4 val = make_float4(0.f, 0.f, 0.f, 0.f);
        if (n < n_nodes) val = *(const float4*)&x[(size_t)n * DIM + c];
        *(float4*)&lx[r][c] = val;
    }
    __syncthreads();

    const int oc = tid & 63;
    const int nl = tid >> 6;
    float aq[4] = {0, 0, 0, 0}, ak[4] = {0, 0, 0, 0};
    float av[4] = {0, 0, 0, 0}, as_[4] = {0, 0, 0, 0};
    #pragma unroll 8
    for (int kk = 0; kk < DIM; ++kk) {
        const float wqv = lw[0][kk * DIM + oc];
        const float wkv = lw[1][kk * DIM + oc];
        const float wvv = lw[2][kk * DIM + oc];
        const float wsv = lw[3][kk * DIM + oc];
        #pragma unroll
        for (int r = 0; r < 4; ++r) {
            const float xv = lx[nl * 4 + r][kk];
            aq[r]  = fmaf(xv, wqv, aq[r]);
            ak[r]  = fmaf(xv, wkv, ak[r]);
            av[r]  = fmaf(xv, wvv, av[r]);
            as_[r] = fmaf(xv, wsv, as_[r]);
        }
    }
    const float bqv = bq[oc], bkv = bk[oc], bvv = bv[oc], bsv = bsk[oc];
    #pragma unroll
    for (int r = 0; r < 4; ++r) {
        const int n = base + nl * 4 + r;
        if (n < n_nodes) {
            q[(size_t)n * DIM + oc]   = aq[r] + bqv;
            k[(size_t)n * DIM + oc]   = ak[r] + bkv;
            v[(size_t)n * DIM + oc]   = av[r] + bvv;
            agg[(size_t)n * DIM + oc] = as_[r] + bsv;   // root skip, messages added later
        }
    }
}

// ---------------------------------------------------------------------------
// Edge pass 1: e = edge_attr@We, score = dot(q[dst], k[src]+e)/8,
// segment-max via atomicMax on order-preserving uint encoding.
// Optionally stores e (chunk-major [4][E][16]) for the message pass.
// ---------------------------------------------------------------------------
__device__ __forceinline__ unsigned enc_f32(float f) {
    unsigned u = __float_as_uint(f);
    return (u & 0x80000000u) ? ~u : (u | 0x80000000u);
}
__device__ __forceinline__ float dec_f32(unsigned u) {
    return (u & 0x80000000u) ? __uint_as_float(u & 0x7FFFFFFFu)
                             : __uint_as_float(~u);
}

__global__ __launch_bounds__(256) void edge_score_kernel(
    const float* __restrict__ q, const float* __restrict__ k,
    const float* __restrict__ ea, const float* __restrict__ we,
    const int* __restrict__ src, const int* __restrict__ dst,
    float* __restrict__ sc, unsigned int* __restrict__ smax,
    float* __restrict__ e_out, int n_edges, int n_nodes)
{
    const int eid = blockIdx.x * 256 + threadIdx.x;
    if (eid >= n_edges) return;
    int s = src[eid], d = dst[eid];
    s = (s < 0) ? 0 : ((s >= n_nodes) ? n_nodes - 1 : s);
    d = (d < 0) ? 0 : ((d >= n_nodes) ? n_nodes - 1 : d);

    float ear[DEA];
    #pragma unroll
    for (int j = 0; j < DEA / 4; ++j)
        *(float4*)&ear[j * 4] = *(const float4*)&ea[(size_t)eid * DEA + j * 4];

    float score = 0.f;
    #pragma unroll
    for (int hc = 0; hc < 4; ++hc) {
        float acc[16];
        #pragma unroll
        for (int i = 0; i < 16; ++i) acc[i] = 0.f;
        #pragma unroll
        for (int j = 0; j < DEA; ++j) {
            #pragma unroll
            for (int i = 0; i < 16; ++i)   // we[] is thread-uniform -> s_load
                acc[i] = fmaf(ear[j], we[j * DIM + hc * 16 + i], acc[i]);
        }
        float qa[16], ka[16];
        #pragma unroll
        for (int i = 0; i < 4; ++i) {
            *(float4*)&qa[i * 4] = *(const float4*)&q[(size_t)d * DIM + hc * 16 + i * 4];
            *(float4*)&ka[i * 4] = *(const float4*)&k[(size_t)s * DIM + hc * 16 + i * 4];
        }
        #pragma unroll
        for (int i = 0; i < 16; ++i) score = fmaf(qa[i], ka[i] + acc[i], score);
        if (e_out) {
            float4* o4 = (float4*)&e_out[((size_t)hc * n_edges + eid) * 16];
            #pragma unroll
            for (int i = 0; i < 4; ++i)
                o4[i] = make_float4(acc[i * 4 + 0], acc[i * 4 + 1], acc[i * 4 + 2], acc[i * 4 + 3]);
        }
    }
    score *= 0.125f;   // 1/sqrt(64)
    sc[eid] = score;
    atomicMax(&smax[d], enc_f32(score));
}

// ---------------------------------------------------------------------------
// Edge pass 2: a = exp(score - smax[dst]); denom[dst] += a
// ---------------------------------------------------------------------------
__global__ __launch_bounds__(256) void edge_softmax_kernel(
    float* __restrict__ sc, const unsigned int* __restrict__ smax,
    float* __restrict__ den, const int* __restrict__ dst,
    int n_edges, int n_nodes)
{
    const int eid = blockIdx.x * 256 + threadIdx.x;
    if (eid >= n_edges) return;
    int d = dst[eid];
    d = (d < 0) ? 0 : ((d >= n_nodes) ? n_nodes - 1 : d);
    const float m = dec_f32(smax[d]);
    const float a = __expf(sc[eid] - m);
    sc[eid] = a;
    atomicAdd(&den[d], a);
}

// ---------------------------------------------------------------------------
// Edge pass 3: alpha = a/denom[dst]; agg[dst] += alpha*(v[src]+e)
// ---------------------------------------------------------------------------
__global__ __launch_bounds__(256) void edge_msg_kernel(
    const float* __restrict__ v, const float* __restrict__ sc,
    const float* __restrict__ den,
    const float* __restrict__ ea, const float* __restrict__ we,
    const float* __restrict__ e_in,
    const int* __restrict__ src, const int* __restrict__ dst,
    float* __restrict__ agg, int n_edges, int n_nodes)
{
    const int eid = blockIdx.x * 256 + threadIdx.x;
    if (eid >= n_edges) return;
    int s = src[eid], d = dst[eid];
    s = (s < 0) ? 0 : ((s >= n_nodes) ? n_nodes - 1 : s);
    d = (d < 0) ? 0 : ((d >= n_nodes) ? n_nodes - 1 : d);
    const float alpha = sc[eid] / den[d];

    float ear[DEA];
    if (!e_in) {
        #pragma unroll
        for (int j = 0; j < DEA / 4; ++j)
            *(float4*)&ear[j * 4] = *(const float4*)&ea[(size_t)eid * DEA + j * 4];
    }
    #pragma unroll
    for (int hc = 0; hc < 4; ++hc) {
        float ech[16];
        if (e_in) {
            const float4* i4 = (const float4*)&e_in[((size_t)hc * n_edges + eid) * 16];
            #pragma unroll
            for (int i = 0; i < 4; ++i) {
                const float4 a4 = i4[i];
                ech[i * 4 + 0] = a4.x; ech[i * 4 + 1] = a4.y;
                ech[i * 4 + 2] = a4.z; ech[i * 4 + 3] = a4.w;
            }
        } else {
            #pragma unroll
            for (int i = 0; i < 16; ++i) ech[i] = 0.f;
            #pragma unroll
            for (int j = 0; j < DEA; ++j) {
                #pragma unroll
                for (int i = 0; i < 16; ++i)
                    ech[i] = fmaf(ear[j], we[j * DIM + hc * 16 + i], ech[i]);
            }
        }
        float va[16];
        #pragma unroll
        for (int i = 0; i < 4; ++i)
            *(float4*)&va[i * 4] = *(const float4*)&v[(size_t)s * DIM + hc * 16 + i * 4];
        #pragma unroll
        for (int i = 0; i < 16; ++i)
            atomicAdd(&agg[(size_t)d * DIM + hc * 16 + i], alpha * (va[i] + ech[i]));
    }
}

// ---------------------------------------------------------------------------
__global__ __launch_bounds__(256) void relu4_kernel(
    const float4* __restrict__ in, float4* __restrict__ out, int n4)
{
    const int i = blockIdx.x * 256 + threadIdx.x;
    if (i < n4) {
        const float4 a = in[i];
        out[i] = make_float4(fmaxf(a.x, 0.f), fmaxf(a.y, 0.f),
                             fmaxf(a.z, 0.f), fmaxf(a.w, 0.f));
    }
}

// ---------------------------------------------------------------------------
// Final: out = relu(concat(h1,h2) @ skip_w + skip_b), K=128
// ---------------------------------------------------------------------------
__global__ __launch_bounds__(256) void final_kernel(
    const float* __restrict__ h1, const float* __restrict__ h2,
    const float* __restrict__ w, const float* __restrict__ b,
    float* __restrict__ out, int n_nodes)
{
    __shared__ float lw[128 * DIM];   // 32 KB
    __shared__ float lx[16][128];     // 8 KB
    const int tid = threadIdx.x;
    {
        const float4* s4 = (const float4*)w;
        float4* d4 = (float4*)lw;
        #pragma unroll
        for (int i = 0; i < 8; ++i) d4[tid + i * 256] = s4[tid + i * 256];
    }
    const int base = blockIdx.x * 16;
    {
        #pragma unroll
        for (int t = 0; t < 2; ++t) {
            const int f = tid + t * 256;   // float4 index, 32 per row
            const int r = f >> 5;
            const int cf = f & 31;
            const int n = base + r;
            float4 val = make_float4(0.f, 0.f, 0.f, 0.f);
            if (n < n_nodes) {
                if (cf < 16) val = *(const float4*)&h1[(size_t)n * DIM + cf * 4];
                else         val = *(const float4*)&h2[(size_t)n * DIM + (cf - 16) * 4];
            }
            *(float4*)&lx[r][cf * 4] = val;
        }
    }
    __syncthreads();

    const int oc = tid & 63;
    const int nl = tid >> 6;
    float acc[4] = {0, 0, 0, 0};
    #pragma unroll 8
    for (int kk = 0; kk < 128; ++kk) {
        const float wv = lw[kk * DIM + oc];
        #pragma unroll
        for (int r = 0; r < 4; ++r)
            acc[r] = fmaf(lx[nl * 4 + r][kk], wv, acc[r]);
    }
    const float bv = b[oc];
    #pragma unroll
    for (int r = 0; r < 4; ++r) {
        const int n = base + nl * 4 + r;
        if (n < n_nodes) out[(size_t)n * DIM + oc] = fmaxf(acc[r] + bv, 0.f);
    }
}

// ---------------------------------------------------------------------------
extern "C" void kernel_launch(void* const* d_in, const int* in_sizes, int n_in,
                              void* d_out, int out_size, void* d_ws, size_t ws_size,
                              hipStream_t stream)
{
    const float* x     = (const float*)d_in[0];
    const int*   ei    = (const int*)d_in[1];
    const float* eattr = (const float*)d_in[2];
    const float *q1w = (const float*)d_in[3],  *q1b = (const float*)d_in[4];
    const float *k1w = (const float*)d_in[5],  *k1b = (const float*)d_in[6];
    const float *v1w = (const float*)d_in[7],  *v1b = (const float*)d_in[8];
    const float *e1w = (const float*)d_in[9];
    const float *s1w = (const float*)d_in[10], *s1b = (const float*)d_in[11];
    const float *q2w = (const float*)d_in[12], *q2b = (const float*)d_in[13];
    const float *k2w = (const float*)d_in[14], *k2b = (const float*)d_in[15];
    const float *v2w = (const float*)d_in[16], *v2b = (const float*)d_in[17];
    const float *e2w = (const float*)d_in[18];
    const float *s2w = (const float*)d_in[19], *s2b = (const float*)d_in[20];
    const float *skw = (const float*)d_in[21], *skb = (const float*)d_in[22];

    const int N = in_sizes[0] / DIM;
    const int E = in_sizes[1] / 2;
    const int* src = ei;
    const int* dst = ei + E;

    float* ws = (float*)d_ws;
    const size_t nf = (size_t)N * DIM;
    float* q   = ws;
    float* k   = q + nf;
    float* v   = k + nf;
    float* agg = v + nf;
    float* h1  = agg + nf;
    float* h2  = h1 + nf;
    float* sc  = h2 + nf;
    unsigned int* smax = (unsigned int*)(sc + E);
    float* den = (float*)(smax + N);
    float* e_ws = den + N;
    const size_t base_f = 6 * nf + (size_t)E + 2 * (size_t)N;
    const bool use_e = ws_size >= (base_f + (size_t)E * DIM) * sizeof(float);
    float* e_ptr = use_e ? e_ws : nullptr;

    const int nblk = (N + 15) / 16;
    const int eblk = (E + 255) / 256;
    const int n4   = (int)(nf / 4);
    const int rblk = (n4 + 255) / 256;

    // ---------------- layer 1 ----------------
    hipMemsetAsync(smax, 0, 2 * (size_t)N * sizeof(float), stream);  // smax(enc -inf)=0, den=0
    node_lin_kernel<<<nblk, 256, 0, stream>>>(x, q1w, q1b, k1w, k1b, v1w, v1b,
                                              s1w, s1b, q, k, v, agg, N);
    edge_score_kernel<<<eblk, 256, 0, stream>>>(q, k, eattr, e1w, src, dst,
                                                sc, smax, e_ptr, E, N);
    edge_softmax_kernel<<<eblk, 256, 0, stream>>>(sc, smax, den, dst, E, N);
    edge_msg_kernel<<<eblk, 256, 0, stream>>>(v, sc, den, eattr, e1w, e_ptr,
                                              src, dst, agg, E, N);
    relu4_kernel<<<rblk, 256, 0, stream>>>((const float4*)agg, (float4*)h1, n4);

    // ---------------- layer 2 ----------------
    hipMemsetAsync(smax, 0, 2 * (size_t)N * sizeof(float), stream);
    node_lin_kernel<<<nblk, 256, 0, stream>>>(h1, q2w, q2b, k2w, k2b, v2w, v2b,
                                              s2w, s2b, q, k, v, agg, N);
    edge_score_kernel<<<eblk, 256, 0, stream>>>(q, k, eattr, e2w, src, dst,
                                                sc, smax, e_ptr, E, N);
    edge_softmax_kernel<<<eblk, 256, 0, stream>>>(sc, smax, den, dst, E, N);
    edge_msg_kernel<<<eblk, 256, 0, stream>>>(v, sc, den, eattr, e2w, e_ptr,
                                              src, dst, agg, E, N);
    relu4_kernel<<<rblk, 256, 0, stream>>>((const float4*)agg, (float4*)h2, n4);

    // ---------------- final skip MLP ----------------
    final_kernel<<<nblk, 256, 0, stream>>>(h1, h2, skw, skb, (float*)d_out, N);
}

// Round 2
// 801.497 us; speedup vs baseline: 7.3634x; 7.3634x over previous
//
#include <hip/hip_runtime.h>

#define DIM 64
#define DEA 32

// ---------------------------------------------------------------------------
// Node linear: q = x@Wq+bq, k = x@Wk+bk, v = x@Wv+bv, agg = x@Ws+bs
// ---------------------------------------------------------------------------
__global__ __launch_bounds__(256) void node_lin_kernel(
    const float* __restrict__ x,
    const float* __restrict__ wq, const float* __restrict__ bq,
    const float* __restrict__ wk, const float* __restrict__ bk,
    const float* __restrict__ wv, const float* __restrict__ bv,
    const float* __restrict__ wsk, const float* __restrict__ bsk,
    float* __restrict__ q, float* __restrict__ k, float* __restrict__ v,
    float* __restrict__ agg, int n_nodes)
{
    __shared__ float lw[4][DIM * DIM];   // 64 KB
    __shared__ float lx[16][DIM];        // 4 KB
    const int tid = threadIdx.x;

    {
        const float* srcs[4] = {wq, wk, wv, wsk};
        #pragma unroll
        for (int m = 0; m < 4; ++m) {
            const float4* s4 = (const float4*)srcs[m];
            float4* d4 = (float4*)lw[m];
            #pragma unroll
            for (int i = 0; i < 4; ++i) d4[tid + i * 256] = s4[tid + i * 256];
        }
    }
    const int base = blockIdx.x * 16;
    {
        const int r = tid >> 4;
        const int c = (tid & 15) * 4;
        const int n = base + r;
        float4 val = make_float4(0.f, 0.f, 0.f, 0.f);
        if (n < n_nodes) val = *(const float4*)&x[(size_t)n * DIM + c];
        *(float4*)&lx[r][c] = val;
    }
    __syncthreads();

    const int oc = tid & 63;
    const int nl = tid >> 6;
    float aq[4] = {0, 0, 0, 0}, ak[4] = {0, 0, 0, 0};
    float av[4] = {0, 0, 0, 0}, as_[4] = {0, 0, 0, 0};
    #pragma unroll 8
    for (int kk = 0; kk < DIM; ++kk) {
        const float wqv = lw[0][kk * DIM + oc];
        const float wkv = lw[1][kk * DIM + oc];
        const float wvv = lw[2][kk * DIM + oc];
        const float wsv = lw[3][kk * DIM + oc];
        #pragma unroll
        for (int r = 0; r < 4; ++r) {
            const float xv = lx[nl * 4 + r][kk];
            aq[r]  = fmaf(xv, wqv, aq[r]);
            ak[r]  = fmaf(xv, wkv, ak[r]);
            av[r]  = fmaf(xv, wvv, av[r]);
            as_[r] = fmaf(xv, wsv, as_[r]);
        }
    }
    const float bqv = bq[oc], bkv = bk[oc], bvv = bv[oc], bsv = bsk[oc];
    #pragma unroll
    for (int r = 0; r < 4; ++r) {
        const int n = base + nl * 4 + r;
        if (n < n_nodes) {
            q[(size_t)n * DIM + oc]   = aq[r] + bqv;
            k[(size_t)n * DIM + oc]   = ak[r] + bkv;
            v[(size_t)n * DIM + oc]   = av[r] + bvv;
            agg[(size_t)n * DIM + oc] = as_[r] + bsv;   // root skip
        }
    }
}

// ---------------------------------------------------------------------------
// CSR build over dst: histogram -> exclusive scan -> scatter
// ---------------------------------------------------------------------------
__global__ __launch_bounds__(256) void hist_kernel(
    const int* __restrict__ dst, int* __restrict__ counts, int n_edges, int n_nodes)
{
    const int eid = blockIdx.x * 256 + threadIdx.x;
    if (eid >= n_edges) return;
    int d = dst[eid];
    d = (d < 0) ? 0 : ((d >= n_nodes) ? n_nodes - 1 : d);
    atomicAdd(&counts[d], 1);
}

// single block, 1024 threads, chunked Hillis-Steele scan.
// reads counts[] (== cursor buffer), writes row_ptr[] and cursor[] (exclusive).
__global__ __launch_bounds__(1024) void scan_kernel(
    int* __restrict__ counts_cursor, int* __restrict__ row_ptr, int n)
{
    __shared__ int ls[1024];
    __shared__ int carry;
    const int tid = threadIdx.x;
    if (tid == 0) carry = 0;
    __syncthreads();
    for (int base = 0; base < n; base += 1024) {
        const int idx = base + tid;
        const int val = (idx < n) ? counts_cursor[idx] : 0;
        ls[tid] = val;
        __syncthreads();
        for (int off = 1; off < 1024; off <<= 1) {
            int t = (tid >= off) ? ls[tid - off] : 0;
            __syncthreads();
            if (tid >= off) ls[tid] += t;
            __syncthreads();
        }
        const int excl = ls[tid] - val + carry;
        if (idx < n) { row_ptr[idx] = excl; counts_cursor[idx] = excl; }
        __syncthreads();
        if (tid == 0) carry += ls[1023];
        __syncthreads();
    }
    if (tid == 0) row_ptr[n] = carry;
}

__global__ __launch_bounds__(256) void scatter_kernel(
    const int* __restrict__ dst, int* __restrict__ cursor,
    int* __restrict__ perm, int n_edges, int n_nodes)
{
    const int eid = blockIdx.x * 256 + threadIdx.x;
    if (eid >= n_edges) return;
    int d = dst[eid];
    d = (d < 0) ? 0 : ((d >= n_nodes) ? n_nodes - 1 : d);
    const int pos = atomicAdd(&cursor[d], 1);
    perm[pos] = eid;
}

// ---------------------------------------------------------------------------
// Fused per-node aggregation: one wave per dst node, lane = channel.
// Online softmax in wave-uniform scalars; message in one register per lane.
// h_out = relu(skip + softmax-weighted sum of (v[src]+e)), e = edge_attr@We.
// ---------------------------------------------------------------------------
__global__ __launch_bounds__(256) void fused_edge_kernel(
    const float* __restrict__ q, const float* __restrict__ k,
    const float* __restrict__ v, const float* __restrict__ ea,
    const float* __restrict__ we, const float* __restrict__ aggskip,
    const int* __restrict__ row_ptr, const int* __restrict__ perm,
    const int* __restrict__ src, float* __restrict__ h_out, int n_nodes)
{
    __shared__ float lw[DEA * DIM];   // 8 KB
    const int tid = threadIdx.x;
    {
        const float4* s4 = (const float4*)we;
        float4* d4 = (float4*)lw;
        d4[tid] = s4[tid];
        d4[tid + 256] = s4[tid + 256];
    }
    __syncthreads();

    const int wave = tid >> 6;
    const int ch = tid & 63;
    const int node = blockIdx.x * 4 + wave;
    if (node >= n_nodes) return;

    const float q_ch = q[(size_t)node * DIM + ch];
    const int beg = row_ptr[node], end = row_ptr[node + 1];

    float m = -3.0e38f, l = 0.f, msg = 0.f;
    for (int i = beg; i < end; ++i) {
        const int eid = perm[i];
        int s = src[eid];
        s = (s < 0) ? 0 : ((s >= n_nodes) ? n_nodes - 1 : s);
        const float k_ch = k[(size_t)s * DIM + ch];
        const float v_ch = v[(size_t)s * DIM + ch];

        float e_ch = 0.f;
        const float4* ea4 = (const float4*)(ea + (size_t)eid * DEA);
        #pragma unroll
        for (int jj = 0; jj < 8; ++jj) {     // wave-uniform addr -> broadcast
            const float4 a4 = ea4[jj];
            e_ch = fmaf(a4.x, lw[(jj * 4 + 0) * DIM + ch], e_ch);
            e_ch = fmaf(a4.y, lw[(jj * 4 + 1) * DIM + ch], e_ch);
            e_ch = fmaf(a4.z, lw[(jj * 4 + 2) * DIM + ch], e_ch);
            e_ch = fmaf(a4.w, lw[(jj * 4 + 3) * DIM + ch], e_ch);
        }

        float t = q_ch * (k_ch + e_ch);
        #pragma unroll
        for (int o = 32; o > 0; o >>= 1) t += __shfl_xor(t, o, 64);
        const float score = t * 0.125f;      // 1/sqrt(64)

        const float m_new = fmaxf(m, score);
        const float p     = __expf(score - m_new);
        const float scale = __expf(m - m_new);
        l   = l * scale + p;
        msg = msg * scale + p * (v_ch + e_ch);
        m   = m_new;
    }
    const float inv = (l > 0.f) ? (1.f / l) : 0.f;
    const float out = aggskip[(size_t)node * DIM + ch] + msg * inv;
    h_out[(size_t)node * DIM + ch] = fmaxf(out, 0.f);
}

// ---------------------------------------------------------------------------
// Final: out = relu(concat(h1,h2) @ skip_w + skip_b), K=128
// ---------------------------------------------------------------------------
__global__ __launch_bounds__(256) void final_kernel(
    const float* __restrict__ h1, const float* __restrict__ h2,
    const float* __restrict__ w, const float* __restrict__ b,
    float* __restrict__ out, int n_nodes)
{
    __shared__ float lw[128 * DIM];   // 32 KB
    __shared__ float lx[16][128];     // 8 KB
    const int tid = threadIdx.x;
    {
        const float4* s4 = (const float4*)w;
        float4* d4 = (float4*)lw;
        #pragma unroll
        for (int i = 0; i < 8; ++i) d4[tid + i * 256] = s4[tid + i * 256];
    }
    const int base = blockIdx.x * 16;
    {
        #pragma unroll
        for (int t = 0; t < 2; ++t) {
            const int f = tid + t * 256;
            const int r = f >> 5;
            const int cf = f & 31;
            const int n = base + r;
            float4 val = make_float4(0.f, 0.f, 0.f, 0.f);
            if (n < n_nodes) {
                if (cf < 16) val = *(const float4*)&h1[(size_t)n * DIM + cf * 4];
                else         val = *(const float4*)&h2[(size_t)n * DIM + (cf - 16) * 4];
            }
            *(float4*)&lx[r][cf * 4] = val;
        }
    }
    __syncthreads();

    const int oc = tid & 63;
    const int nl = tid >> 6;
    float acc[4] = {0, 0, 0, 0};
    #pragma unroll 8
    for (int kk = 0; kk < 128; ++kk) {
        const float wv = lw[kk * DIM + oc];
        #pragma unroll
        for (int r = 0; r < 4; ++r)
            acc[r] = fmaf(lx[nl * 4 + r][kk], wv, acc[r]);
    }
    const float bv = b[oc];
    #pragma unroll
    for (int r = 0; r < 4; ++r) {
        const int n = base + nl * 4 + r;
        if (n < n_nodes) out[(size_t)n * DIM + oc] = fmaxf(acc[r] + bv, 0.f);
    }
}

// ---------------------------------------------------------------------------
extern "C" void kernel_launch(void* const* d_in, const int* in_sizes, int n_in,
                              void* d_out, int out_size, void* d_ws, size_t ws_size,
                              hipStream_t stream)
{
    const float* x     = (const float*)d_in[0];
    const int*   ei    = (const int*)d_in[1];
    const float* eattr = (const float*)d_in[2];
    const float *q1w = (const float*)d_in[3],  *q1b = (const float*)d_in[4];
    const float *k1w = (const float*)d_in[5],  *k1b = (const float*)d_in[6];
    const float *v1w = (const float*)d_in[7],  *v1b = (const float*)d_in[8];
    const float *e1w = (const float*)d_in[9];
    const float *s1w = (const float*)d_in[10], *s1b = (const float*)d_in[11];
    const float *q2w = (const float*)d_in[12], *q2b = (const float*)d_in[13];
    const float *k2w = (const float*)d_in[14], *k2b = (const float*)d_in[15];
    const float *v2w = (const float*)d_in[16], *v2b = (const float*)d_in[17];
    const float *e2w = (const float*)d_in[18];
    const float *s2w = (const float*)d_in[19], *s2b = (const float*)d_in[20];
    const float *skw = (const float*)d_in[21], *skb = (const float*)d_in[22];

    const int N = in_sizes[0] / DIM;
    const int E = in_sizes[1] / 2;
    const int* src = ei;
    const int* dst = ei + E;

    float* ws = (float*)d_ws;
    const size_t nf = (size_t)N * DIM;
    float* q   = ws;
    float* k   = q + nf;
    float* v   = k + nf;
    float* agg = v + nf;
    float* h1  = agg + nf;
    float* h2  = h1 + nf;
    int* row_ptr = (int*)(h2 + nf);      // N+1
    int* cursor  = row_ptr + N + 1;      // N  (doubles as histogram counts)
    int* perm    = cursor + N;           // E

    const int nblk = (N + 15) / 16;
    const int eblk = (E + 255) / 256;
    const int fblk = (N + 3) / 4;

    // ---------------- CSR over dst (shared by both layers) ----------------
    hipMemsetAsync(cursor, 0, (size_t)N * sizeof(int), stream);
    hist_kernel<<<eblk, 256, 0, stream>>>(dst, cursor, E, N);
    scan_kernel<<<1, 1024, 0, stream>>>(cursor, row_ptr, N);
    scatter_kernel<<<eblk, 256, 0, stream>>>(dst, cursor, perm, E, N);

    // ---------------- layer 1 ----------------
    node_lin_kernel<<<nblk, 256, 0, stream>>>(x, q1w, q1b, k1w, k1b, v1w, v1b,
                                              s1w, s1b, q, k, v, agg, N);
    fused_edge_kernel<<<fblk, 256, 0, stream>>>(q, k, v, eattr, e1w, agg,
                                                row_ptr, perm, src, h1, N);

    // ---------------- layer 2 ----------------
    node_lin_kernel<<<nblk, 256, 0, stream>>>(h1, q2w, q2b, k2w, k2b, v2w, v2b,
                                              s2w, s2b, q, k, v, agg, N);
    fused_edge_kernel<<<fblk, 256, 0, stream>>>(q, k, v, eattr, e2w, agg,
                                                row_ptr, perm, src, h2, N);

    // ---------------- final skip MLP ----------------
    final_kernel<<<nblk, 256, 0, stream>>>(h1, h2, skw, skb, (float*)d_out, N);
}